// Round 8
// baseline (5196.236 us; speedup 1.0000x reference)
//
#include <hip/hip_runtime.h>
#include <hip/hip_bf16.h>

#define N_NODES 200000
#define N_EDGES 400000
#define N_GRAPHS 4096
#define HDIM 300
#define H2DIM 600
#define NLAYERS 5

typedef __hip_bfloat16 bf16;
typedef __attribute__((ext_vector_type(4))) short s16x4;
typedef __attribute__((ext_vector_type(8))) short s16x8;
typedef __attribute__((ext_vector_type(4))) float f32x4v;

__device__ inline short f2bf(float f) {
    __hip_bfloat16 b = __float2bfloat16(f);
    return *(short*)&b;
}
__device__ inline float bf2f(short s) {
    __hip_bfloat16 b = *(__hip_bfloat16*)&s;
    return __bfloat162float(b);
}

// ---------------------------------------------------------------------------
// Diagnostic (ws too small): report ws_size MB via d_out
// ---------------------------------------------------------------------------
__global__ void diag_kernel(float* __restrict__ out, int n, float val) {
    int i = blockIdx.x * blockDim.x + threadIdx.x;
    if (i < n) out[i] = val;
}

// ---------------------------------------------------------------------------
// Edge sort by dst: histogram -> scan -> scatter.
// ---------------------------------------------------------------------------
__global__ void hist_kernel(const int* __restrict__ edge_index, int* __restrict__ offs) {
    int e = blockIdx.x * blockDim.x + threadIdx.x;
    if (e >= N_EDGES) return;
    atomicAdd(&offs[edge_index[N_EDGES + e]], 1);
}

#define SCAN_N 200001
__global__ void scan1_kernel(int* __restrict__ offs, int* __restrict__ bsum) {
    __shared__ int ls[256];
    int tid = threadIdx.x;
    int base = blockIdx.x * 1024 + tid * 4;
    int v[4];
#pragma unroll
    for (int j = 0; j < 4; j++) v[j] = (base + j < SCAN_N) ? offs[base + j] : 0;
    int t = v[0] + v[1] + v[2] + v[3];
    ls[tid] = t;
    __syncthreads();
    for (int off = 1; off < 256; off <<= 1) {
        int y = (tid >= off) ? ls[tid - off] : 0;
        __syncthreads();
        ls[tid] += y;
        __syncthreads();
    }
    int ex = ls[tid] - t;
#pragma unroll
    for (int j = 0; j < 4; j++) {
        if (base + j < SCAN_N) offs[base + j] = ex;
        ex += v[j];
    }
    if (tid == 255) bsum[blockIdx.x] = ls[255];
}

__global__ void scan2_kernel(int* __restrict__ bsum, int nb) {
    __shared__ int ls[256];
    int tid = threadIdx.x;
    int v = (tid < nb) ? bsum[tid] : 0;
    ls[tid] = v;
    __syncthreads();
    for (int off = 1; off < 256; off <<= 1) {
        int y = (tid >= off) ? ls[tid - off] : 0;
        __syncthreads();
        ls[tid] += y;
        __syncthreads();
    }
    if (tid < nb) bsum[tid] = ls[tid] - v;
}

__global__ void scan3_kernel(int* __restrict__ offs, const int* __restrict__ bsum) {
    int i = blockIdx.x * blockDim.x + threadIdx.x;
    if (i >= SCAN_N) return;
    offs[i] += bsum[i >> 10];
}

__global__ void scatter_kernel(const int* __restrict__ edge_index,
                               const int* __restrict__ edge_attr,
                               int* __restrict__ offs,
                               int* __restrict__ sidx) {
    int e = blockIdx.x * blockDim.x + threadIdx.x;
    if (e >= N_EDGES) return;
    int src = edge_index[e];
    int dst = edge_index[N_EDGES + e];
    int combo = edge_attr[e * 3 + 0] | (edge_attr[e * 3 + 1] << 4) | (edge_attr[e * 3 + 2] << 8);
    int pos = atomicAdd(&offs[dst], 1);
    sidx[pos] = src | (combo << 18);
}

// ---------------------------------------------------------------------------
// Bond-embedding table: etab[combo][c] (stride 304), bf16
// ---------------------------------------------------------------------------
__global__ void etab_kernel(const float* __restrict__ bond_l, short* __restrict__ etab) {
    int idx = blockIdx.x * blockDim.x + threadIdx.x;
    if (idx >= 4096 * 304) return;
    int combo = idx / 304;
    int c = idx - combo * 304;
    if (c >= HDIM) { etab[idx] = 0; return; }
    int a0 = combo & 15, a1 = (combo >> 4) & 15, a2 = combo >> 8;
    float v = bond_l[a0 * HDIM + c] + bond_l[16 * HDIM + a1 * HDIM + c]
            + bond_l[32 * HDIM + a2 * HDIM + c];
    etab[idx] = f2bf(v);
}

// ---------------------------------------------------------------------------
// Weight swizzle into MFMA B-fragment order.
// Wt1s: [l][nt(40)][kb(10)][lane(64)][8]; Wt2s: [l][nt(20)][kb(20)][lane(64)][8]
// ---------------------------------------------------------------------------
__global__ void prep_w_swz(const float* __restrict__ W1, const float* __restrict__ W2,
                           short* __restrict__ Wt1s, short* __restrict__ Wt2s) {
    int idx = blockIdx.x * blockDim.x + threadIdx.x;
    const int G1 = NLAYERS * 40 * 10 * 64;
    const int G2 = NLAYERS * 20 * 20 * 64;
    if (idx < G1) {
        int l = idx / (40 * 10 * 64);
        int r = idx - l * (40 * 10 * 64);
        int nt = r / (10 * 64);
        int r2 = r - nt * (10 * 64);
        int kb = r2 >> 6;
        int lane = r2 & 63;
        int n = nt * 16 + (lane & 15);
        int k0 = kb * 32 + (lane >> 4) * 8;
        s16x8 o;
#pragma unroll
        for (int j = 0; j < 8; j++) {
            int k = k0 + j;
            float v = (n < H2DIM && k < HDIM) ? W1[((size_t)l * HDIM + k) * H2DIM + n] : 0.f;
            o[j] = f2bf(v);
        }
        *(s16x8*)&Wt1s[(size_t)idx * 8] = o;
    } else if (idx < G1 + G2) {
        int t = idx - G1;
        int l = t / (20 * 20 * 64);
        int r = t - l * (20 * 20 * 64);
        int nt = r / (20 * 64);
        int r2 = r - nt * (20 * 64);
        int kb = r2 >> 6;
        int lane = r2 & 63;
        int n = nt * 16 + (lane & 15);
        int k0 = kb * 32 + (lane >> 4) * 8;
        s16x8 o;
#pragma unroll
        for (int j = 0; j < 8; j++) {
            int k = k0 + j;
            float v = (n < HDIM && k < H2DIM) ? W2[((size_t)l * H2DIM + k) * HDIM + n] : 0.f;
            o[j] = f2bf(v);
        }
        *(s16x8*)&Wt2s[(size_t)t * 8] = o;
    }
}

// ---------------------------------------------------------------------------
// AtomEncoder -> h bf16 (vectorized: one thread per 4 cols)
// ---------------------------------------------------------------------------
__global__ void atom_kernel(const int* __restrict__ x,
                            const float* __restrict__ atom_emb,
                            short* __restrict__ h) {
    int i = blockIdx.x * blockDim.x + threadIdx.x;
    if (i >= N_NODES * 75) return;
    int n = i / 75;
    int c = (i - n * 75) * 4;
    const int* xr = x + n * 9;
    float4 s = {0.f, 0.f, 0.f, 0.f};
#pragma unroll
    for (int f = 0; f < 9; f++) {
        float4 v = *(const float4*)&atom_emb[(size_t)(f * 120 + xr[f]) * HDIM + c];
        s.x += v.x; s.y += v.y; s.z += v.z; s.w += v.w;
    }
    s16x4 o = {f2bf(s.x), f2bf(s.y), f2bf(s.z), f2bf(s.w)};
    *(s16x4*)&h[(size_t)n * HDIM + c] = o;
}

// ---------------------------------------------------------------------------
// Aggregation kernel (unchanged)
// ---------------------------------------------------------------------------
__launch_bounds__(256)
__global__ void agg_kernel(const short* __restrict__ h_in,
                           short* __restrict__ z,
                           const int* __restrict__ offs,
                           const int* __restrict__ sidx,
                           const short* __restrict__ etab,
                           const float* __restrict__ eps, int l) {
    int tid = threadIdx.x;
    int q = tid >> 4;
    int l16 = tid & 15;
    int n = blockIdx.x * 16 + q;
    float e1 = 1.f + eps[l];
    int beg = (n == 0) ? 0 : offs[n - 1];
    int end = offs[n];

    float4 acc[5];
#pragma unroll
    for (int j = 0; j < 5; j++) acc[j] = (float4){0.f, 0.f, 0.f, 0.f};
    bool tail = l16 < 11;
    int ctail = 256 + l16 * 4;

    int e = beg;
    for (; e + 2 <= end; e += 2) {
        int pk0 = sidx[e];
        int pk1 = sidx[e + 1];
        const short* hr0 = h_in + (size_t)(pk0 & 0x3FFFF) * HDIM;
        const short* er0 = etab + (((unsigned)pk0) >> 18) * 304;
        const short* hr1 = h_in + (size_t)(pk1 & 0x3FFFF) * HDIM;
        const short* er1 = etab + (((unsigned)pk1) >> 18) * 304;
        s16x4 hv0[5], ev0[5], hv1[5], ev1[5];
#pragma unroll
        for (int rep = 0; rep < 4; rep++) {
            int c = rep * 64 + l16 * 4;
            hv0[rep] = *(const s16x4*)(hr0 + c);
            ev0[rep] = *(const s16x4*)(er0 + c);
            hv1[rep] = *(const s16x4*)(hr1 + c);
            ev1[rep] = *(const s16x4*)(er1 + c);
        }
        if (tail) {
            hv0[4] = *(const s16x4*)(hr0 + ctail);
            ev0[4] = *(const s16x4*)(er0 + ctail);
            hv1[4] = *(const s16x4*)(hr1 + ctail);
            ev1[4] = *(const s16x4*)(er1 + ctail);
        }
#pragma unroll
        for (int rep = 0; rep < 5; rep++) {
            if (rep == 4 && !tail) continue;
            acc[rep].x += fmaxf(0.f, bf2f(hv0[rep].x) + bf2f(ev0[rep].x))
                        + fmaxf(0.f, bf2f(hv1[rep].x) + bf2f(ev1[rep].x));
            acc[rep].y += fmaxf(0.f, bf2f(hv0[rep].y) + bf2f(ev0[rep].y))
                        + fmaxf(0.f, bf2f(hv1[rep].y) + bf2f(ev1[rep].y));
            acc[rep].z += fmaxf(0.f, bf2f(hv0[rep].z) + bf2f(ev0[rep].z))
                        + fmaxf(0.f, bf2f(hv1[rep].z) + bf2f(ev1[rep].z));
            acc[rep].w += fmaxf(0.f, bf2f(hv0[rep].w) + bf2f(ev0[rep].w))
                        + fmaxf(0.f, bf2f(hv1[rep].w) + bf2f(ev1[rep].w));
        }
    }
    if (e < end) {
        int pk0 = sidx[e];
        const short* hr0 = h_in + (size_t)(pk0 & 0x3FFFF) * HDIM;
        const short* er0 = etab + (((unsigned)pk0) >> 18) * 304;
        s16x4 hv0[5], ev0[5];
#pragma unroll
        for (int rep = 0; rep < 4; rep++) {
            int c = rep * 64 + l16 * 4;
            hv0[rep] = *(const s16x4*)(hr0 + c);
            ev0[rep] = *(const s16x4*)(er0 + c);
        }
        if (tail) {
            hv0[4] = *(const s16x4*)(hr0 + ctail);
            ev0[4] = *(const s16x4*)(er0 + ctail);
        }
#pragma unroll
        for (int rep = 0; rep < 5; rep++) {
            if (rep == 4 && !tail) continue;
            acc[rep].x += fmaxf(0.f, bf2f(hv0[rep].x) + bf2f(ev0[rep].x));
            acc[rep].y += fmaxf(0.f, bf2f(hv0[rep].y) + bf2f(ev0[rep].y));
            acc[rep].z += fmaxf(0.f, bf2f(hv0[rep].z) + bf2f(ev0[rep].z));
            acc[rep].w += fmaxf(0.f, bf2f(hv0[rep].w) + bf2f(ev0[rep].w));
        }
    }

    const short* hn = h_in + (size_t)n * HDIM;
    short* zr = z + (size_t)n * HDIM;
#pragma unroll
    for (int rep = 0; rep < 5; rep++) {
        if (rep == 4 && !tail) continue;
        int c = rep < 4 ? rep * 64 + l16 * 4 : ctail;
        s16x4 hv = *(const s16x4*)(hn + c);
        s16x4 o;
        o.x = f2bf(fmaf(e1, bf2f(hv.x), acc[rep].x));
        o.y = f2bf(fmaf(e1, bf2f(hv.y), acc[rep].y));
        o.z = f2bf(fmaf(e1, bf2f(hv.z), acc[rep].z));
        o.w = f2bf(fmaf(e1, bf2f(hv.w), acc[rep].w));
        *(s16x4*)(zr + c) = o;
    }
}

// ---------------------------------------------------------------------------
// MLP kernel v10: v7 per-wave structure at 3 blocks/CU.
// v9 lesson: occupancy gains must keep per-wave MFMA:LDS-op ratio. Here the
// 40 KB Zs LDS is deleted entirely — stage-1 a-frags are read DIRECT from
// global z (16 rows x 64 contiguous B per frag set, L2/L3-hot; k>=300
// spill-reads next row, killed by W zero-pad). Extra L2 traffic ~2.5 GB vs
// 34.5 TB/s ceiling: not binding. LDS = Ys 17408 + 32-row h-stage bounce
// 19200 = 36608 B -> 3 blocks/CU at __launch_bounds__(256,3) (VGPR cap 170;
// est ~160, WRITE_SIZE is the spill tripwire). Stage-1 is barrier-free:
// 10 k-steps of {6 independent global loads + 8 MFMA}, 3 waves/SIMD.
// Ys epilogue/stage-2/W mappings verbatim from passing v7.
// ---------------------------------------------------------------------------
#define YST 136
#define YS_SHORTS (64 * YST)                   /* 8704 shorts = 17408 B */
#define HST_OFF YS_SHORTS
#define LDS_SHORTS (YS_SHORTS + 32 * HDIM)     /* 18304 shorts = 36608 B */

__launch_bounds__(256, 3)
__global__ void mlp_kernel(const short* __restrict__ zin,
                           short* __restrict__ hout,
                           const short* __restrict__ Wt1,
                           const short* __restrict__ Wt2,
                           const float* __restrict__ b1l,
                           const float* __restrict__ gammal,
                           const float* __restrict__ betal,
                           const float* __restrict__ meanl,
                           const float* __restrict__ varl,
                           const float* __restrict__ b2l) {
    __shared__ short lds[LDS_SHORTS];
    int tid = threadIdx.x;
    int wng = tid >> 6;          // wave = N-group 0..3
    int lane = tid & 63;
    int quad = lane >> 4;
    int l16 = lane & 15;
    int row0 = blockIdx.x * 64;
    const short* zrow = zin + (size_t)row0 * HDIM;

    f32x4v acc2[4][5];
#pragma unroll
    for (int rt = 0; rt < 4; rt++)
#pragma unroll
        for (int ct = 0; ct < 5; ct++) acc2[rt][ct] = (f32x4v){0.f, 0.f, 0.f, 0.f};

    for (int cc = 0; cc < 5; cc++) {
        // ---------- stage 1: C1[64 x 128] = Z @ W1[:, cc*128..+127] ----------
        // barrier-free: a-frags direct from global z, b-frags from global W1
        f32x4v acc1[4][2];
#pragma unroll
        for (int rt = 0; rt < 4; rt++)
#pragma unroll
            for (int ct = 0; ct < 2; ct++) acc1[rt][ct] = (f32x4v){0.f, 0.f, 0.f, 0.f};

#pragma unroll
        for (int kb = 0; kb < 10; kb++) {
            s16x8 b[2];
#pragma unroll
            for (int ct = 0; ct < 2; ct++)
                b[ct] = *(const s16x8*)&Wt1[
                    ((size_t)(((cc * 8 + wng * 2 + ct) * 10 + kb) * 64) + lane) * 8];
            int ks = kb * 32 + quad * 8;
            s16x8 a[4];
#pragma unroll
            for (int rt = 0; rt < 4; rt++)
                a[rt] = *(const s16x8*)&zrow[(size_t)(rt * 16 + l16) * HDIM + ks];
#pragma unroll
            for (int ct = 0; ct < 2; ct++)
#pragma unroll
                for (int rt = 0; rt < 4; rt++)
                    acc1[rt][ct] = __builtin_amdgcn_mfma_f32_16x16x32_bf16(
                        a[rt], b[ct], acc1[rt][ct], 0, 0, 0);
        }
        __syncthreads();   // previous cc's Ys readers done
        // ---------- epilogue: BN + ReLU -> Ys (verbatim v7, base 0) ----------
#pragma unroll
        for (int ct = 0; ct < 2; ct++) {
            int kc = wng * 32 + ct * 16 + l16;
            int col = cc * 128 + kc;
            bool valid = col < H2DIM;
            float s = 0.f, sh = 0.f;
            if (valid) {
                s = gammal[col] * rsqrtf(varl[col] + 1e-5f);
                sh = betal[col] + (b1l[col] - meanl[col]) * s;
            }
#pragma unroll
            for (int rt = 0; rt < 4; rt++)
#pragma unroll
                for (int rr = 0; rr < 4; rr++) {
                    float v = valid ? fmaxf(0.f, fmaf(acc1[rt][ct][rr], s, sh)) : 0.f;
                    lds[(rt * 16 + quad * 4 + rr) * YST + kc] = f2bf(v);
                }
        }
        __syncthreads();   // Ys published
        // ---------- stage 2: acc2 += Ys @ W2[cc*128.., :] (verbatim v7) ----------
#pragma unroll
        for (int kbl = 0; kbl < 4; kbl++) {
            s16x8 b[5];
#pragma unroll
            for (int ct = 0; ct < 5; ct++)
                b[ct] = *(const s16x8*)&Wt2[
                    ((size_t)(((wng * 5 + ct) * 20 + cc * 4 + kbl) * 64) + lane) * 8];
            int ks = kbl * 32 + quad * 8;
            s16x8 a[4];
#pragma unroll
            for (int rt = 0; rt < 4; rt++)
                a[rt] = *(const s16x8*)&lds[(rt * 16 + l16) * YST + ks];
#pragma unroll
            for (int ct = 0; ct < 5; ct++)
#pragma unroll
                for (int rt = 0; rt < 4; rt++)
                    acc2[rt][ct] = __builtin_amdgcn_mfma_f32_16x16x32_bf16(
                        a[rt], b[ct], acc2[rt][ct], 0, 0, 0);
        }
    }

    // ---------- final epilogue: two 32-row halves through the h-stage
    // LDS bounce (hstage disjoint from Ys, so first writes need no barrier) ----
#pragma unroll
    for (int half = 0; half < 2; half++) {
#pragma unroll
        for (int rt2 = 0; rt2 < 2; rt2++) {
            int rt = half * 2 + rt2;
#pragma unroll
            for (int ct = 0; ct < 5; ct++) {
                int col = wng * 80 + ct * 16 + l16;
                if (col < HDIM) {
                    float bb = b2l[col];
#pragma unroll
                    for (int rr = 0; rr < 4; rr++) {
                        int rrow = rt2 * 16 + quad * 4 + rr;
                        lds[HST_OFF + rrow * HDIM + col] = f2bf(acc2[rt][ct][rr] + bb);
                    }
                }
            }
        }
        __syncthreads();   // half's h-stage writes done
        for (int i = tid; i < 32 * 75; i += 256) {
            *(s16x4*)&hout[(size_t)(row0 + half * 32) * HDIM + i * 4] =
                *(const s16x4*)&lds[HST_OFF + i * 4];
        }
        if (half == 0) __syncthreads();   // copy-out reads done before overwrite
    }
}

// ---------------------------------------------------------------------------
// Mean pool per graph (batch sorted) + classifier (vectorized)
// ---------------------------------------------------------------------------
__device__ int lower_bound_dev(const int* a, int n, int v) {
    int lo = 0, hi = n;
    while (lo < hi) {
        int mid = (lo + hi) >> 1;
        if (a[mid] < v) lo = mid + 1; else hi = mid;
    }
    return lo;
}

__global__ void pool_kernel(const short* __restrict__ h,
                            const int* __restrict__ batch,
                            const float* __restrict__ cls_W,
                            const float* __restrict__ cls_b,
                            float* __restrict__ out) {
    __shared__ int seg[2];
    __shared__ float r0s[256], r1s[256];
    int g = blockIdx.x;
    int t = threadIdx.x;
    if (t == 0) {
        seg[0] = lower_bound_dev(batch, N_NODES, g);
        seg[1] = lower_bound_dev(batch, N_NODES, g + 1);
    }
    __syncthreads();
    int s = seg[0], e = seg[1];
    float inv = 1.f / fmaxf((float)(e - s), 1.f);
    float p0 = 0.f, p1 = 0.f;
    if (t < 75) {
        int c = t * 4;
        float4 sum = {0.f, 0.f, 0.f, 0.f};
        for (int n = s; n < e; n++) {
            s16x4 v = *(const s16x4*)&h[(size_t)n * HDIM + c];
            sum.x += bf2f(v.x);
            sum.y += bf2f(v.y);
            sum.z += bf2f(v.z);
            sum.w += bf2f(v.w);
        }
        float4 gf = {sum.x * inv, sum.y * inv, sum.z * inv, sum.w * inv};
        *(float4*)&out[2 * N_GRAPHS + (size_t)g * HDIM + c] = gf;
        p0 = gf.x * cls_W[c * 2] + gf.y * cls_W[(c + 1) * 2]
           + gf.z * cls_W[(c + 2) * 2] + gf.w * cls_W[(c + 3) * 2];
        p1 = gf.x * cls_W[c * 2 + 1] + gf.y * cls_W[(c + 1) * 2 + 1]
           + gf.z * cls_W[(c + 2) * 2 + 1] + gf.w * cls_W[(c + 3) * 2 + 1];
    }
    r0s[t] = p0;
    r1s[t] = p1;
    __syncthreads();
    for (int st = 128; st > 0; st >>= 1) {
        if (t < st) { r0s[t] += r0s[t + st]; r1s[t] += r1s[t + st]; }
        __syncthreads();
    }
    if (t == 0) {
        out[g * 2 + 0] = r0s[0] + cls_b[0];
        out[g * 2 + 1] = r1s[0] + cls_b[1];
    }
}

// ---------------------------------------------------------------------------
extern "C" void kernel_launch(void* const* d_in, const int* in_sizes, int n_in,
                              void* d_out, int out_size, void* d_ws, size_t ws_size,
                              hipStream_t stream) {
    const int* x          = (const int*)d_in[0];
    const int* edge_index = (const int*)d_in[1];
    const int* edge_attr  = (const int*)d_in[2];
    const int* batch      = (const int*)d_in[3];
    const float* atom_emb = (const float*)d_in[4];
    const float* bond_emb = (const float*)d_in[5];
    const float* eps      = (const float*)d_in[6];
    const float* W1       = (const float*)d_in[7];
    const float* b1       = (const float*)d_in[8];
    const float* bn_gamma = (const float*)d_in[9];
    const float* bn_beta  = (const float*)d_in[10];
    const float* bn_mean  = (const float*)d_in[11];
    const float* bn_var   = (const float*)d_in[12];
    const float* W2       = (const float*)d_in[13];
    const float* b2       = (const float*)d_in[14];
    const float* cls_W    = (const float*)d_in[15];
    const float* cls_b    = (const float*)d_in[16];
    float* out = (float*)d_out;

    char* base = (char*)d_ws;
    const size_t OFF_HA   = 0;                       // 120,000,000
    const size_t OFF_HB   = 120000000;               // 120,000,000 (z / ping-pong)
    const size_t OFF_WT1  = 240000000;               //   2,048,000
    const size_t OFF_WT2  = 242048000;               //   2,048,000
    const size_t OFF_ETAB = 244096000;               //   2,490,368
    const size_t OFF_SIDX = 246586368;               //   1,600,000
    const size_t OFF_OFFS = 248186368;               //     800,016
    const size_t OFF_BSUM = 248986384;               //         784
    const size_t TOTAL    = 248987168;

    if (ws_size < TOTAL) {
        float mb = (float)(ws_size >> 20);
        diag_kernel<<<(out_size + 255) / 256, 256, 0, stream>>>(out, out_size, mb);
        return;
    }

    short* hA   = (short*)(base + OFF_HA);
    short* hB   = (short*)(base + OFF_HB);
    short* Wt1s = (short*)(base + OFF_WT1);
    short* Wt2s = (short*)(base + OFF_WT2);
    short* etab = (short*)(base + OFF_ETAB);
    int*   sidx = (int*)(base + OFF_SIDX);
    int*   offs = (int*)(base + OFF_OFFS);
    int*   bsum = (int*)(base + OFF_BSUM);

    // ---- edge sort by dst ----
    hipMemsetAsync(offs, 0, SCAN_N * sizeof(int), stream);
    hist_kernel<<<(N_EDGES + 255) / 256, 256, 0, stream>>>(edge_index, offs);
    scan1_kernel<<<196, 256, 0, stream>>>(offs, bsum);
    scan2_kernel<<<1, 256, 0, stream>>>(bsum, 196);
    scan3_kernel<<<(SCAN_N + 255) / 256, 256, 0, stream>>>(offs, bsum);
    scatter_kernel<<<(N_EDGES + 255) / 256, 256, 0, stream>>>(edge_index, edge_attr, offs, sidx);

    // ---- weight swizzle + atom encoder ----
    {
        int total = NLAYERS * 40 * 10 * 64 + NLAYERS * 20 * 20 * 64;
        prep_w_swz<<<(total + 255) / 256, 256, 0, stream>>>(W1, W2, Wt1s, Wt2s);
    }
    atom_kernel<<<(N_NODES * 75 + 255) / 256, 256, 0, stream>>>(x, atom_emb, hA);

    // ---- layers: agg hA->hB(z), mlp hB->hA ----
    for (int l = 0; l < NLAYERS; l++) {
        etab_kernel<<<(4096 * 304 + 255) / 256, 256, 0, stream>>>(
            bond_emb + (size_t)l * 3 * 16 * HDIM, etab);
        agg_kernel<<<N_NODES / 16, 256, 0, stream>>>(
            hA, hB, offs, sidx, etab, eps, l);
        mlp_kernel<<<N_NODES / 64, 256, 0, stream>>>(
            hB, hA,
            Wt1s + (size_t)l * 640 * 320, Wt2s + (size_t)l * 320 * 640,
            b1 + l * H2DIM, bn_gamma + l * H2DIM, bn_beta + l * H2DIM,
            bn_mean + l * H2DIM, bn_var + l * H2DIM, b2 + l * HDIM);
    }

    // ---- pool + classifier ----
    pool_kernel<<<N_GRAPHS, 256, 0, stream>>>(hA, batch, cls_W, cls_b, out);
}

// Round 9
// 4949.855 us; speedup vs baseline: 1.0498x; 1.0498x over previous
//
#include <hip/hip_runtime.h>
#include <hip/hip_bf16.h>

#define N_NODES 200000
#define N_EDGES 400000
#define N_GRAPHS 4096
#define HDIM 300
#define H2DIM 600
#define NLAYERS 5

typedef __hip_bfloat16 bf16;
typedef __attribute__((ext_vector_type(4))) short s16x4;
typedef __attribute__((ext_vector_type(8))) short s16x8;
typedef __attribute__((ext_vector_type(4))) float f32x4v;

__device__ inline short f2bf(float f) {
    __hip_bfloat16 b = __float2bfloat16(f);
    return *(short*)&b;
}
__device__ inline float bf2f(short s) {
    __hip_bfloat16 b = *(__hip_bfloat16*)&s;
    return __bfloat162float(b);
}

// ---------------------------------------------------------------------------
// Diagnostic (ws too small): report ws_size MB via d_out
// ---------------------------------------------------------------------------
__global__ void diag_kernel(float* __restrict__ out, int n, float val) {
    int i = blockIdx.x * blockDim.x + threadIdx.x;
    if (i < n) out[i] = val;
}

// ---------------------------------------------------------------------------
// Edge sort by dst: histogram -> scan -> scatter.
// ---------------------------------------------------------------------------
__global__ void hist_kernel(const int* __restrict__ edge_index, int* __restrict__ offs) {
    int e = blockIdx.x * blockDim.x + threadIdx.x;
    if (e >= N_EDGES) return;
    atomicAdd(&offs[edge_index[N_EDGES + e]], 1);
}

#define SCAN_N 200001
__global__ void scan1_kernel(int* __restrict__ offs, int* __restrict__ bsum) {
    __shared__ int ls[256];
    int tid = threadIdx.x;
    int base = blockIdx.x * 1024 + tid * 4;
    int v[4];
#pragma unroll
    for (int j = 0; j < 4; j++) v[j] = (base + j < SCAN_N) ? offs[base + j] : 0;
    int t = v[0] + v[1] + v[2] + v[3];
    ls[tid] = t;
    __syncthreads();
    for (int off = 1; off < 256; off <<= 1) {
        int y = (tid >= off) ? ls[tid - off] : 0;
        __syncthreads();
        ls[tid] += y;
        __syncthreads();
    }
    int ex = ls[tid] - t;
#pragma unroll
    for (int j = 0; j < 4; j++) {
        if (base + j < SCAN_N) offs[base + j] = ex;
        ex += v[j];
    }
    if (tid == 255) bsum[blockIdx.x] = ls[255];
}

__global__ void scan2_kernel(int* __restrict__ bsum, int nb) {
    __shared__ int ls[256];
    int tid = threadIdx.x;
    int v = (tid < nb) ? bsum[tid] : 0;
    ls[tid] = v;
    __syncthreads();
    for (int off = 1; off < 256; off <<= 1) {
        int y = (tid >= off) ? ls[tid - off] : 0;
        __syncthreads();
        ls[tid] += y;
        __syncthreads();
    }
    if (tid < nb) bsum[tid] = ls[tid] - v;
}

__global__ void scan3_kernel(int* __restrict__ offs, const int* __restrict__ bsum) {
    int i = blockIdx.x * blockDim.x + threadIdx.x;
    if (i >= SCAN_N) return;
    offs[i] += bsum[i >> 10];
}

__global__ void scatter_kernel(const int* __restrict__ edge_index,
                               const int* __restrict__ edge_attr,
                               int* __restrict__ offs,
                               int* __restrict__ sidx) {
    int e = blockIdx.x * blockDim.x + threadIdx.x;
    if (e >= N_EDGES) return;
    int src = edge_index[e];
    int dst = edge_index[N_EDGES + e];
    int combo = edge_attr[e * 3 + 0] | (edge_attr[e * 3 + 1] << 4) | (edge_attr[e * 3 + 2] << 8);
    int pos = atomicAdd(&offs[dst], 1);
    sidx[pos] = src | (combo << 18);
}

// ---------------------------------------------------------------------------
// Bond-embedding table: etab[combo][c] (stride 304), bf16
// ---------------------------------------------------------------------------
__global__ void etab_kernel(const float* __restrict__ bond_l, short* __restrict__ etab) {
    int idx = blockIdx.x * blockDim.x + threadIdx.x;
    if (idx >= 4096 * 304) return;
    int combo = idx / 304;
    int c = idx - combo * 304;
    if (c >= HDIM) { etab[idx] = 0; return; }
    int a0 = combo & 15, a1 = (combo >> 4) & 15, a2 = combo >> 8;
    float v = bond_l[a0 * HDIM + c] + bond_l[16 * HDIM + a1 * HDIM + c]
            + bond_l[32 * HDIM + a2 * HDIM + c];
    etab[idx] = f2bf(v);
}

// ---------------------------------------------------------------------------
// Weight swizzle into MFMA B-fragment order.
// Wt1s: [l][nt(40)][kb(10)][lane(64)][8]; Wt2s: [l][nt(20)][kb(20)][lane(64)][8]
// ---------------------------------------------------------------------------
__global__ void prep_w_swz(const float* __restrict__ W1, const float* __restrict__ W2,
                           short* __restrict__ Wt1s, short* __restrict__ Wt2s) {
    int idx = blockIdx.x * blockDim.x + threadIdx.x;
    const int G1 = NLAYERS * 40 * 10 * 64;
    const int G2 = NLAYERS * 20 * 20 * 64;
    if (idx < G1) {
        int l = idx / (40 * 10 * 64);
        int r = idx - l * (40 * 10 * 64);
        int nt = r / (10 * 64);
        int r2 = r - nt * (10 * 64);
        int kb = r2 >> 6;
        int lane = r2 & 63;
        int n = nt * 16 + (lane & 15);
        int k0 = kb * 32 + (lane >> 4) * 8;
        s16x8 o;
#pragma unroll
        for (int j = 0; j < 8; j++) {
            int k = k0 + j;
            float v = (n < H2DIM && k < HDIM) ? W1[((size_t)l * HDIM + k) * H2DIM + n] : 0.f;
            o[j] = f2bf(v);
        }
        *(s16x8*)&Wt1s[(size_t)idx * 8] = o;
    } else if (idx < G1 + G2) {
        int t = idx - G1;
        int l = t / (20 * 20 * 64);
        int r = t - l * (20 * 20 * 64);
        int nt = r / (20 * 64);
        int r2 = r - nt * (20 * 64);
        int kb = r2 >> 6;
        int lane = r2 & 63;
        int n = nt * 16 + (lane & 15);
        int k0 = kb * 32 + (lane >> 4) * 8;
        s16x8 o;
#pragma unroll
        for (int j = 0; j < 8; j++) {
            int k = k0 + j;
            float v = (n < HDIM && k < H2DIM) ? W2[((size_t)l * H2DIM + k) * HDIM + n] : 0.f;
            o[j] = f2bf(v);
        }
        *(s16x8*)&Wt2s[(size_t)t * 8] = o;
    }
}

// ---------------------------------------------------------------------------
// AtomEncoder -> h bf16 (vectorized: one thread per 4 cols)
// ---------------------------------------------------------------------------
__global__ void atom_kernel(const int* __restrict__ x,
                            const float* __restrict__ atom_emb,
                            short* __restrict__ h) {
    int i = blockIdx.x * blockDim.x + threadIdx.x;
    if (i >= N_NODES * 75) return;
    int n = i / 75;
    int c = (i - n * 75) * 4;
    const int* xr = x + n * 9;
    float4 s = {0.f, 0.f, 0.f, 0.f};
#pragma unroll
    for (int f = 0; f < 9; f++) {
        float4 v = *(const float4*)&atom_emb[(size_t)(f * 120 + xr[f]) * HDIM + c];
        s.x += v.x; s.y += v.y; s.z += v.z; s.w += v.w;
    }
    s16x4 o = {f2bf(s.x), f2bf(s.y), f2bf(s.z), f2bf(s.w)};
    *(s16x4*)&h[(size_t)n * HDIM + c] = o;
}

// ---------------------------------------------------------------------------
// Aggregation kernel (unchanged)
// ---------------------------------------------------------------------------
__launch_bounds__(256)
__global__ void agg_kernel(const short* __restrict__ h_in,
                           short* __restrict__ z,
                           const int* __restrict__ offs,
                           const int* __restrict__ sidx,
                           const short* __restrict__ etab,
                           const float* __restrict__ eps, int l) {
    int tid = threadIdx.x;
    int q = tid >> 4;
    int l16 = tid & 15;
    int n = blockIdx.x * 16 + q;
    float e1 = 1.f + eps[l];
    int beg = (n == 0) ? 0 : offs[n - 1];
    int end = offs[n];

    float4 acc[5];
#pragma unroll
    for (int j = 0; j < 5; j++) acc[j] = (float4){0.f, 0.f, 0.f, 0.f};
    bool tail = l16 < 11;
    int ctail = 256 + l16 * 4;

    int e = beg;
    for (; e + 2 <= end; e += 2) {
        int pk0 = sidx[e];
        int pk1 = sidx[e + 1];
        const short* hr0 = h_in + (size_t)(pk0 & 0x3FFFF) * HDIM;
        const short* er0 = etab + (((unsigned)pk0) >> 18) * 304;
        const short* hr1 = h_in + (size_t)(pk1 & 0x3FFFF) * HDIM;
        const short* er1 = etab + (((unsigned)pk1) >> 18) * 304;
        s16x4 hv0[5], ev0[5], hv1[5], ev1[5];
#pragma unroll
        for (int rep = 0; rep < 4; rep++) {
            int c = rep * 64 + l16 * 4;
            hv0[rep] = *(const s16x4*)(hr0 + c);
            ev0[rep] = *(const s16x4*)(er0 + c);
            hv1[rep] = *(const s16x4*)(hr1 + c);
            ev1[rep] = *(const s16x4*)(er1 + c);
        }
        if (tail) {
            hv0[4] = *(const s16x4*)(hr0 + ctail);
            ev0[4] = *(const s16x4*)(er0 + ctail);
            hv1[4] = *(const s16x4*)(hr1 + ctail);
            ev1[4] = *(const s16x4*)(er1 + ctail);
        }
#pragma unroll
        for (int rep = 0; rep < 5; rep++) {
            if (rep == 4 && !tail) continue;
            acc[rep].x += fmaxf(0.f, bf2f(hv0[rep].x) + bf2f(ev0[rep].x))
                        + fmaxf(0.f, bf2f(hv1[rep].x) + bf2f(ev1[rep].x));
            acc[rep].y += fmaxf(0.f, bf2f(hv0[rep].y) + bf2f(ev0[rep].y))
                        + fmaxf(0.f, bf2f(hv1[rep].y) + bf2f(ev1[rep].y));
            acc[rep].z += fmaxf(0.f, bf2f(hv0[rep].z) + bf2f(ev0[rep].z))
                        + fmaxf(0.f, bf2f(hv1[rep].z) + bf2f(ev1[rep].z));
            acc[rep].w += fmaxf(0.f, bf2f(hv0[rep].w) + bf2f(ev0[rep].w))
                        + fmaxf(0.f, bf2f(hv1[rep].w) + bf2f(ev1[rep].w));
        }
    }
    if (e < end) {
        int pk0 = sidx[e];
        const short* hr0 = h_in + (size_t)(pk0 & 0x3FFFF) * HDIM;
        const short* er0 = etab + (((unsigned)pk0) >> 18) * 304;
        s16x4 hv0[5], ev0[5];
#pragma unroll
        for (int rep = 0; rep < 4; rep++) {
            int c = rep * 64 + l16 * 4;
            hv0[rep] = *(const s16x4*)(hr0 + c);
            ev0[rep] = *(const s16x4*)(er0 + c);
        }
        if (tail) {
            hv0[4] = *(const s16x4*)(hr0 + ctail);
            ev0[4] = *(const s16x4*)(er0 + ctail);
        }
#pragma unroll
        for (int rep = 0; rep < 5; rep++) {
            if (rep == 4 && !tail) continue;
            acc[rep].x += fmaxf(0.f, bf2f(hv0[rep].x) + bf2f(ev0[rep].x));
            acc[rep].y += fmaxf(0.f, bf2f(hv0[rep].y) + bf2f(ev0[rep].y));
            acc[rep].z += fmaxf(0.f, bf2f(hv0[rep].z) + bf2f(ev0[rep].z));
            acc[rep].w += fmaxf(0.f, bf2f(hv0[rep].w) + bf2f(ev0[rep].w));
        }
    }

    const short* hn = h_in + (size_t)n * HDIM;
    short* zr = z + (size_t)n * HDIM;
#pragma unroll
    for (int rep = 0; rep < 5; rep++) {
        if (rep == 4 && !tail) continue;
        int c = rep < 4 ? rep * 64 + l16 * 4 : ctail;
        s16x4 hv = *(const s16x4*)(hn + c);
        s16x4 o;
        o.x = f2bf(fmaf(e1, bf2f(hv.x), acc[rep].x));
        o.y = f2bf(fmaf(e1, bf2f(hv.y), acc[rep].y));
        o.z = f2bf(fmaf(e1, bf2f(hv.z), acc[rep].z));
        o.w = f2bf(fmaf(e1, bf2f(hv.w), acc[rep].w));
        *(s16x4*)(zr + c) = o;
    }
}

// ---------------------------------------------------------------------------
// MLP kernel v11: v7 structure with DOUBLED stage-1 MFMA density.
// Latency model (validated by v7/v8/v9/v10 counters): k-step time
// T = M + max(0, 300 - T) with M = MFMA pipe-cyc/step; v7 stage-1 M=80 ->
// util 24% (matches 22%). Here each wave owns 4 stage-1 n-tiles (256-col cc
// blocks, 3 outer iters): M=160 -> predicted util ~45% in stage-1.
// Ys widens to 256 cols, YST=264, XOR-swizzled (kills v7's residual 4e6
// bank conflicts = stage-2 8-way Ys reads). Liveness guards (compile-time
// under unroll, wave-uniform) skip dead tiles nt>=38 / k-blocks kb>=19;
// skipped work only multiplies zero-padded W/Ys columns -> exact results.
// LDS: Zs 40960 + Ys 33792 = 74752 B -> 2 blocks/CU. Barriers 12 -> 8.
// VGPR est ~210 (acc 144 + transient); WRITE_SIZE is the spill tripwire.
// ---------------------------------------------------------------------------
#define ZSTRIDE 320
#define YS_OFF (64 * ZSTRIDE)                  /* 20480 shorts */
#define YST 264
#define LDS_SHORTS (YS_OFF + 64 * YST)         /* 37376 shorts = 74752 B */

__launch_bounds__(256, 2)
__global__ void mlp_kernel(const short* __restrict__ zin,
                           short* __restrict__ hout,
                           const short* __restrict__ Wt1,
                           const short* __restrict__ Wt2,
                           const float* __restrict__ b1l,
                           const float* __restrict__ gammal,
                           const float* __restrict__ betal,
                           const float* __restrict__ meanl,
                           const float* __restrict__ varl,
                           const float* __restrict__ b2l) {
    __shared__ short lds[LDS_SHORTS];
    int tid = threadIdx.x;
    int wng = tid >> 6;          // wave 0..3
    int lane = tid & 63;
    int quad = lane >> 4;
    int l16 = lane & 15;
    int row0 = blockIdx.x * 64;

    // ---- stage Zs: 64 rows x 320 shorts, XOR-swizzled 16B chunks (v4+) ----
    {
        const short* zbase = zin + (size_t)row0 * HDIM;
        for (int i = tid; i < 64 * 40; i += 256) {
            int r = i / 40;
            int cs = i - r * 40;
            const short* srcp = zbase + r * HDIM + cs * 8;
            s16x4 v0 = *(const s16x4*)srcp;
            s16x4 v1 = *(const s16x4*)(srcp + 4);
            int d = r * ZSTRIDE + ((cs ^ (r & 7)) << 3);
            *(s16x4*)&lds[d] = v0;
            *(s16x4*)&lds[d + 4] = v1;
        }
    }

    f32x4v acc2[4][5];
#pragma unroll
    for (int rt = 0; rt < 4; rt++)
#pragma unroll
        for (int ct = 0; ct < 5; ct++) acc2[rt][ct] = (f32x4v){0.f, 0.f, 0.f, 0.f};

    __syncthreads();   // Zs published

    for (int cc = 0; cc < 3; cc++) {
        // ---------- stage 1: C1[64 x 256] = Z @ W1[:, cc*256..+255] ----------
        // wave owns n-tiles cc*16 + wng*4 + ct (ct 0..3); live iff nt < 38
        f32x4v acc1[4][4];
#pragma unroll
        for (int rt = 0; rt < 4; rt++)
#pragma unroll
            for (int ct = 0; ct < 4; ct++) acc1[rt][ct] = (f32x4v){0.f, 0.f, 0.f, 0.f};

        int ntb = cc * 16 + wng * 4;
#pragma unroll
        for (int kb = 0; kb < 10; kb++) {
            s16x8 b[4];
#pragma unroll
            for (int ct = 0; ct < 4; ct++)
                if (ntb + ct < 38)
                    b[ct] = *(const s16x8*)&Wt1[
                        ((size_t)(((ntb + ct) * 10 + kb) * 64) + lane) * 8];
            int ks = kb * 32 + quad * 8;
            s16x8 a[4];
#pragma unroll
            for (int rt = 0; rt < 4; rt++)
                a[rt] = *(const s16x8*)&lds[(rt * 16 + l16) * ZSTRIDE
                                            + (ks ^ ((l16 & 7) << 3))];
#pragma unroll
            for (int ct = 0; ct < 4; ct++)
                if (ntb + ct < 38)
#pragma unroll
                    for (int rt = 0; rt < 4; rt++)
                        acc1[rt][ct] = __builtin_amdgcn_mfma_f32_16x16x32_bf16(
                            a[rt], b[ct], acc1[rt][ct], 0, 0, 0);
        }
        __syncthreads();   // previous cc's Ys readers done
        // ---------- epilogue: BN + ReLU -> Ys[64 x 256] (swizzled) ----------
#pragma unroll
        for (int ct = 0; ct < 4; ct++) {
            int kc = (wng * 4 + ct) * 16 + l16;     // 0..255
            int col = cc * 256 + kc;
            bool valid = col < H2DIM;
            float s = 0.f, sh = 0.f;
            if (valid) {
                s = gammal[col] * rsqrtf(varl[col] + 1e-5f);
                sh = betal[col] + (b1l[col] - meanl[col]) * s;
            }
#pragma unroll
            for (int rt = 0; rt < 4; rt++)
#pragma unroll
                for (int rr = 0; rr < 4; rr++) {
                    int row = rt * 16 + quad * 4 + rr;
                    float v = valid ? fmaxf(0.f, fmaf(acc1[rt][ct][rr], s, sh)) : 0.f;
                    lds[YS_OFF + row * YST + (kc ^ ((row & 7) << 3))] = f2bf(v);
                }
        }
        __syncthreads();   // Ys published
        // ---------- stage 2: acc2 += Ys @ W2[cc*256.., :] ----------
#pragma unroll
        for (int kbl = 0; kbl < 8; kbl++) {
            if (cc * 8 + kbl >= 19) continue;   // kb 0..18 live (k<608)
            int kbg = cc * 8 + kbl;
            s16x8 b[5];
#pragma unroll
            for (int ct = 0; ct < 5; ct++)
                b[ct] = *(const s16x8*)&Wt2[
                    ((size_t)(((wng * 5 + ct) * 20 + kbg) * 64) + lane) * 8];
            int ks = kbl * 32 + quad * 8;
            s16x8 a[4];
#pragma unroll
            for (int rt = 0; rt < 4; rt++) {
                int row = rt * 16 + l16;
                a[rt] = *(const s16x8*)&lds[YS_OFF + row * YST
                                            + (ks ^ ((row & 7) << 3))];
            }
#pragma unroll
            for (int ct = 0; ct < 5; ct++)
#pragma unroll
                for (int rt = 0; rt < 4; rt++)
                    acc2[rt][ct] = __builtin_amdgcn_mfma_f32_16x16x32_bf16(
                        a[rt], b[ct], acc2[rt][ct], 0, 0, 0);
        }
    }

    // ---------- final epilogue: h-tile (stride 300) into Zs region, then
    // coalesced contiguous copy-out (verbatim v7; Zs region is dead) ----------
#pragma unroll
    for (int ct = 0; ct < 5; ct++) {
        int col = wng * 80 + ct * 16 + l16;
        if (col < HDIM) {
            float bb = b2l[col];
#pragma unroll
            for (int rt = 0; rt < 4; rt++)
#pragma unroll
                for (int rr = 0; rr < 4; rr++) {
                    int rrow = rt * 16 + quad * 4 + rr;
                    lds[rrow * HDIM + col] = f2bf(acc2[rt][ct][rr] + bb);
                }
        }
    }
    __syncthreads();
    for (int i = tid; i < 64 * 75; i += 256) {
        *(s16x4*)&hout[(size_t)row0 * HDIM + i * 4] = *(const s16x4*)&lds[i * 4];
    }
}

// ---------------------------------------------------------------------------
// Mean pool per graph (batch sorted) + classifier (vectorized)
// ---------------------------------------------------------------------------
__device__ int lower_bound_dev(const int* a, int n, int v) {
    int lo = 0, hi = n;
    while (lo < hi) {
        int mid = (lo + hi) >> 1;
        if (a[mid] < v) lo = mid + 1; else hi = mid;
    }
    return lo;
}

__global__ void pool_kernel(const short* __restrict__ h,
                            const int* __restrict__ batch,
                            const float* __restrict__ cls_W,
                            const float* __restrict__ cls_b,
                            float* __restrict__ out) {
    __shared__ int seg[2];
    __shared__ float r0s[256], r1s[256];
    int g = blockIdx.x;
    int t = threadIdx.x;
    if (t == 0) {
        seg[0] = lower_bound_dev(batch, N_NODES, g);
        seg[1] = lower_bound_dev(batch, N_NODES, g + 1);
    }
    __syncthreads();
    int s = seg[0], e = seg[1];
    float inv = 1.f / fmaxf((float)(e - s), 1.f);
    float p0 = 0.f, p1 = 0.f;
    if (t < 75) {
        int c = t * 4;
        float4 sum = {0.f, 0.f, 0.f, 0.f};
        for (int n = s; n < e; n++) {
            s16x4 v = *(const s16x4*)&h[(size_t)n * HDIM + c];
            sum.x += bf2f(v.x);
            sum.y += bf2f(v.y);
            sum.z += bf2f(v.z);
            sum.w += bf2f(v.w);
        }
        float4 gf = {sum.x * inv, sum.y * inv, sum.z * inv, sum.w * inv};
        *(float4*)&out[2 * N_GRAPHS + (size_t)g * HDIM + c] = gf;
        p0 = gf.x * cls_W[c * 2] + gf.y * cls_W[(c + 1) * 2]
           + gf.z * cls_W[(c + 2) * 2] + gf.w * cls_W[(c + 3) * 2];
        p1 = gf.x * cls_W[c * 2 + 1] + gf.y * cls_W[(c + 1) * 2 + 1]
           + gf.z * cls_W[(c + 2) * 2 + 1] + gf.w * cls_W[(c + 3) * 2 + 1];
    }
    r0s[t] = p0;
    r1s[t] = p1;
    __syncthreads();
    for (int st = 128; st > 0; st >>= 1) {
        if (t < st) { r0s[t] += r0s[t + st]; r1s[t] += r1s[t + st]; }
        __syncthreads();
    }
    if (t == 0) {
        out[g * 2 + 0] = r0s[0] + cls_b[0];
        out[g * 2 + 1] = r1s[0] + cls_b[1];
    }
}

// ---------------------------------------------------------------------------
extern "C" void kernel_launch(void* const* d_in, const int* in_sizes, int n_in,
                              void* d_out, int out_size, void* d_ws, size_t ws_size,
                              hipStream_t stream) {
    const int* x          = (const int*)d_in[0];
    const int* edge_index = (const int*)d_in[1];
    const int* edge_attr  = (const int*)d_in[2];
    const int* batch      = (const int*)d_in[3];
    const float* atom_emb = (const float*)d_in[4];
    const float* bond_emb = (const float*)d_in[5];
    const float* eps      = (const float*)d_in[6];
    const float* W1       = (const float*)d_in[7];
    const float* b1       = (const float*)d_in[8];
    const float* bn_gamma = (const float*)d_in[9];
    const float* bn_beta  = (const float*)d_in[10];
    const float* bn_mean  = (const float*)d_in[11];
    const float* bn_var   = (const float*)d_in[12];
    const float* W2       = (const float*)d_in[13];
    const float* b2       = (const float*)d_in[14];
    const float* cls_W    = (const float*)d_in[15];
    const float* cls_b    = (const float*)d_in[16];
    float* out = (float*)d_out;

    char* base = (char*)d_ws;
    const size_t OFF_HA   = 0;                       // 120,000,000
    const size_t OFF_HB   = 120000000;               // 120,000,000 (z / ping-pong)
    const size_t OFF_WT1  = 240000000;               //   2,048,000
    const size_t OFF_WT2  = 242048000;               //   2,048,000
    const size_t OFF_ETAB = 244096000;               //   2,490,368
    const size_t OFF_SIDX = 246586368;               //   1,600,000
    const size_t OFF_OFFS = 248186368;               //     800,016
    const size_t OFF_BSUM = 248986384;               //         784
    const size_t TOTAL    = 248987168;

    if (ws_size < TOTAL) {
        float mb = (float)(ws_size >> 20);
        diag_kernel<<<(out_size + 255) / 256, 256, 0, stream>>>(out, out_size, mb);
        return;
    }

    short* hA   = (short*)(base + OFF_HA);
    short* hB   = (short*)(base + OFF_HB);
    short* Wt1s = (short*)(base + OFF_WT1);
    short* Wt2s = (short*)(base + OFF_WT2);
    short* etab = (short*)(base + OFF_ETAB);
    int*   sidx = (int*)(base + OFF_SIDX);
    int*   offs = (int*)(base + OFF_OFFS);
    int*   bsum = (int*)(base + OFF_BSUM);

    // ---- edge sort by dst ----
    hipMemsetAsync(offs, 0, SCAN_N * sizeof(int), stream);
    hist_kernel<<<(N_EDGES + 255) / 256, 256, 0, stream>>>(edge_index, offs);
    scan1_kernel<<<196, 256, 0, stream>>>(offs, bsum);
    scan2_kernel<<<1, 256, 0, stream>>>(bsum, 196);
    scan3_kernel<<<(SCAN_N + 255) / 256, 256, 0, stream>>>(offs, bsum);
    scatter_kernel<<<(N_EDGES + 255) / 256, 256, 0, stream>>>(edge_index, edge_attr, offs, sidx);

    // ---- weight swizzle + atom encoder ----
    {
        int total = NLAYERS * 40 * 10 * 64 + NLAYERS * 20 * 20 * 64;
        prep_w_swz<<<(total + 255) / 256, 256, 0, stream>>>(W1, W2, Wt1s, Wt2s);
    }
    atom_kernel<<<(N_NODES * 75 + 255) / 256, 256, 0, stream>>>(x, atom_emb, hA);

    // ---- layers: agg hA->hB(z), mlp hB->hA ----
    for (int l = 0; l < NLAYERS; l++) {
        etab_kernel<<<(4096 * 304 + 255) / 256, 256, 0, stream>>>(
            bond_emb + (size_t)l * 3 * 16 * HDIM, etab);
        agg_kernel<<<N_NODES / 16, 256, 0, stream>>>(
            hA, hB, offs, sidx, etab, eps, l);
        mlp_kernel<<<N_NODES / 64, 256, 0, stream>>>(
            hB, hA,
            Wt1s + (size_t)l * 640 * 320, Wt2s + (size_t)l * 320 * 640,
            b1 + l * H2DIM, bn_gamma + l * H2DIM, bn_beta + l * H2DIM,
            bn_mean + l * H2DIM, bn_var + l * H2DIM, b2 + l * HDIM);
    }

    // ---- pool + classifier ----
    pool_kernel<<<N_GRAPHS, 256, 0, stream>>>(hA, batch, cls_W, cls_b, out);
}

// Round 10
// 2262.010 us; speedup vs baseline: 2.2972x; 2.1883x over previous
//
#include <hip/hip_runtime.h>
#include <hip/hip_bf16.h>

#define N_NODES 200000
#define N_EDGES 400000
#define N_GRAPHS 4096
#define HDIM 300
#define H2DIM 600
#define NLAYERS 5

typedef __hip_bfloat16 bf16;
typedef __attribute__((ext_vector_type(4))) short s16x4;
typedef __attribute__((ext_vector_type(8))) short s16x8;
typedef __attribute__((ext_vector_type(4))) float f32x4v;

__device__ inline short f2bf(float f) {
    __hip_bfloat16 b = __float2bfloat16(f);
    return *(short*)&b;
}
__device__ inline float bf2f(short s) {
    __hip_bfloat16 b = *(__hip_bfloat16*)&s;
    return __bfloat162float(b);
}

// ---------------------------------------------------------------------------
// Diagnostic (ws too small): report ws_size MB via d_out
// ---------------------------------------------------------------------------
__global__ void diag_kernel(float* __restrict__ out, int n, float val) {
    int i = blockIdx.x * blockDim.x + threadIdx.x;
    if (i < n) out[i] = val;
}

// ---------------------------------------------------------------------------
// Edge sort by dst: histogram -> scan -> scatter.
// ---------------------------------------------------------------------------
__global__ void hist_kernel(const int* __restrict__ edge_index, int* __restrict__ offs) {
    int e = blockIdx.x * blockDim.x + threadIdx.x;
    if (e >= N_EDGES) return;
    atomicAdd(&offs[edge_index[N_EDGES + e]], 1);
}

#define SCAN_N 200001
__global__ void scan1_kernel(int* __restrict__ offs, int* __restrict__ bsum) {
    __shared__ int ls[256];
    int tid = threadIdx.x;
    int base = blockIdx.x * 1024 + tid * 4;
    int v[4];
#pragma unroll
    for (int j = 0; j < 4; j++) v[j] = (base + j < SCAN_N) ? offs[base + j] : 0;
    int t = v[0] + v[1] + v[2] + v[3];
    ls[tid] = t;
    __syncthreads();
    for (int off = 1; off < 256; off <<= 1) {
        int y = (tid >= off) ? ls[tid - off] : 0;
        __syncthreads();
        ls[tid] += y;
        __syncthreads();
    }
    int ex = ls[tid] - t;
#pragma unroll
    for (int j = 0; j < 4; j++) {
        if (base + j < SCAN_N) offs[base + j] = ex;
        ex += v[j];
    }
    if (tid == 255) bsum[blockIdx.x] = ls[255];
}

__global__ void scan2_kernel(int* __restrict__ bsum, int nb) {
    __shared__ int ls[256];
    int tid = threadIdx.x;
    int v = (tid < nb) ? bsum[tid] : 0;
    ls[tid] = v;
    __syncthreads();
    for (int off = 1; off < 256; off <<= 1) {
        int y = (tid >= off) ? ls[tid - off] : 0;
        __syncthreads();
        ls[tid] += y;
        __syncthreads();
    }
    if (tid < nb) bsum[tid] = ls[tid] - v;
}

__global__ void scan3_kernel(int* __restrict__ offs, const int* __restrict__ bsum) {
    int i = blockIdx.x * blockDim.x + threadIdx.x;
    if (i >= SCAN_N) return;
    offs[i] += bsum[i >> 10];
}

__global__ void scatter_kernel(const int* __restrict__ edge_index,
                               const int* __restrict__ edge_attr,
                               int* __restrict__ offs,
                               int* __restrict__ sidx) {
    int e = blockIdx.x * blockDim.x + threadIdx.x;
    if (e >= N_EDGES) return;
    int src = edge_index[e];
    int dst = edge_index[N_EDGES + e];
    int combo = edge_attr[e * 3 + 0] | (edge_attr[e * 3 + 1] << 4) | (edge_attr[e * 3 + 2] << 8);
    int pos = atomicAdd(&offs[dst], 1);
    sidx[pos] = src | (combo << 18);
}

// ---------------------------------------------------------------------------
// Bond-embedding table: etab[combo][c] (stride 304), bf16
// ---------------------------------------------------------------------------
__global__ void etab_kernel(const float* __restrict__ bond_l, short* __restrict__ etab) {
    int idx = blockIdx.x * blockDim.x + threadIdx.x;
    if (idx >= 4096 * 304) return;
    int combo = idx / 304;
    int c = idx - combo * 304;
    if (c >= HDIM) { etab[idx] = 0; return; }
    int a0 = combo & 15, a1 = (combo >> 4) & 15, a2 = combo >> 8;
    float v = bond_l[a0 * HDIM + c] + bond_l[16 * HDIM + a1 * HDIM + c]
            + bond_l[32 * HDIM + a2 * HDIM + c];
    etab[idx] = f2bf(v);
}

// ---------------------------------------------------------------------------
// Weight swizzle into MFMA B-fragment order.
// Wt1s: [l][nt(40)][kb(10)][lane(64)][8]; Wt2s: [l][nt(20)][kb(20)][lane(64)][8]
// ---------------------------------------------------------------------------
__global__ void prep_w_swz(const float* __restrict__ W1, const float* __restrict__ W2,
                           short* __restrict__ Wt1s, short* __restrict__ Wt2s) {
    int idx = blockIdx.x * blockDim.x + threadIdx.x;
    const int G1 = NLAYERS * 40 * 10 * 64;
    const int G2 = NLAYERS * 20 * 20 * 64;
    if (idx < G1) {
        int l = idx / (40 * 10 * 64);
        int r = idx - l * (40 * 10 * 64);
        int nt = r / (10 * 64);
        int r2 = r - nt * (10 * 64);
        int kb = r2 >> 6;
        int lane = r2 & 63;
        int n = nt * 16 + (lane & 15);
        int k0 = kb * 32 + (lane >> 4) * 8;
        s16x8 o;
#pragma unroll
        for (int j = 0; j < 8; j++) {
            int k = k0 + j;
            float v = (n < H2DIM && k < HDIM) ? W1[((size_t)l * HDIM + k) * H2DIM + n] : 0.f;
            o[j] = f2bf(v);
        }
        *(s16x8*)&Wt1s[(size_t)idx * 8] = o;
    } else if (idx < G1 + G2) {
        int t = idx - G1;
        int l = t / (20 * 20 * 64);
        int r = t - l * (20 * 20 * 64);
        int nt = r / (20 * 64);
        int r2 = r - nt * (20 * 64);
        int kb = r2 >> 6;
        int lane = r2 & 63;
        int n = nt * 16 + (lane & 15);
        int k0 = kb * 32 + (lane >> 4) * 8;
        s16x8 o;
#pragma unroll
        for (int j = 0; j < 8; j++) {
            int k = k0 + j;
            float v = (n < HDIM && k < H2DIM) ? W2[((size_t)l * H2DIM + k) * HDIM + n] : 0.f;
            o[j] = f2bf(v);
        }
        *(s16x8*)&Wt2s[(size_t)t * 8] = o;
    }
}

// ---------------------------------------------------------------------------
// AtomEncoder -> h bf16 (vectorized: one thread per 4 cols)
// ---------------------------------------------------------------------------
__global__ void atom_kernel(const int* __restrict__ x,
                            const float* __restrict__ atom_emb,
                            short* __restrict__ h) {
    int i = blockIdx.x * blockDim.x + threadIdx.x;
    if (i >= N_NODES * 75) return;
    int n = i / 75;
    int c = (i - n * 75) * 4;
    const int* xr = x + n * 9;
    float4 s = {0.f, 0.f, 0.f, 0.f};
#pragma unroll
    for (int f = 0; f < 9; f++) {
        float4 v = *(const float4*)&atom_emb[(size_t)(f * 120 + xr[f]) * HDIM + c];
        s.x += v.x; s.y += v.y; s.z += v.z; s.w += v.w;
    }
    s16x4 o = {f2bf(s.x), f2bf(s.y), f2bf(s.z), f2bf(s.w)};
    *(s16x4*)&h[(size_t)n * HDIM + c] = o;
}

// ---------------------------------------------------------------------------
// Aggregation kernel (unchanged)
// ---------------------------------------------------------------------------
__launch_bounds__(256)
__global__ void agg_kernel(const short* __restrict__ h_in,
                           short* __restrict__ z,
                           const int* __restrict__ offs,
                           const int* __restrict__ sidx,
                           const short* __restrict__ etab,
                           const float* __restrict__ eps, int l) {
    int tid = threadIdx.x;
    int q = tid >> 4;
    int l16 = tid & 15;
    int n = blockIdx.x * 16 + q;
    float e1 = 1.f + eps[l];
    int beg = (n == 0) ? 0 : offs[n - 1];
    int end = offs[n];

    float4 acc[5];
#pragma unroll
    for (int j = 0; j < 5; j++) acc[j] = (float4){0.f, 0.f, 0.f, 0.f};
    bool tail = l16 < 11;
    int ctail = 256 + l16 * 4;

    int e = beg;
    for (; e + 2 <= end; e += 2) {
        int pk0 = sidx[e];
        int pk1 = sidx[e + 1];
        const short* hr0 = h_in + (size_t)(pk0 & 0x3FFFF) * HDIM;
        const short* er0 = etab + (((unsigned)pk0) >> 18) * 304;
        const short* hr1 = h_in + (size_t)(pk1 & 0x3FFFF) * HDIM;
        const short* er1 = etab + (((unsigned)pk1) >> 18) * 304;
        s16x4 hv0[5], ev0[5], hv1[5], ev1[5];
#pragma unroll
        for (int rep = 0; rep < 4; rep++) {
            int c = rep * 64 + l16 * 4;
            hv0[rep] = *(const s16x4*)(hr0 + c);
            ev0[rep] = *(const s16x4*)(er0 + c);
            hv1[rep] = *(const s16x4*)(hr1 + c);
            ev1[rep] = *(const s16x4*)(er1 + c);
        }
        if (tail) {
            hv0[4] = *(const s16x4*)(hr0 + ctail);
            ev0[4] = *(const s16x4*)(er0 + ctail);
            hv1[4] = *(const s16x4*)(hr1 + ctail);
            ev1[4] = *(const s16x4*)(er1 + ctail);
        }
#pragma unroll
        for (int rep = 0; rep < 5; rep++) {
            if (rep == 4 && !tail) continue;
            acc[rep].x += fmaxf(0.f, bf2f(hv0[rep].x) + bf2f(ev0[rep].x))
                        + fmaxf(0.f, bf2f(hv1[rep].x) + bf2f(ev1[rep].x));
            acc[rep].y += fmaxf(0.f, bf2f(hv0[rep].y) + bf2f(ev0[rep].y))
                        + fmaxf(0.f, bf2f(hv1[rep].y) + bf2f(ev1[rep].y));
            acc[rep].z += fmaxf(0.f, bf2f(hv0[rep].z) + bf2f(ev0[rep].z))
                        + fmaxf(0.f, bf2f(hv1[rep].z) + bf2f(ev1[rep].z));
            acc[rep].w += fmaxf(0.f, bf2f(hv0[rep].w) + bf2f(ev0[rep].w))
                        + fmaxf(0.f, bf2f(hv1[rep].w) + bf2f(ev1[rep].w));
        }
    }
    if (e < end) {
        int pk0 = sidx[e];
        const short* hr0 = h_in + (size_t)(pk0 & 0x3FFFF) * HDIM;
        const short* er0 = etab + (((unsigned)pk0) >> 18) * 304;
        s16x4 hv0[5], ev0[5];
#pragma unroll
        for (int rep = 0; rep < 4; rep++) {
            int c = rep * 64 + l16 * 4;
            hv0[rep] = *(const s16x4*)(hr0 + c);
            ev0[rep] = *(const s16x4*)(er0 + c);
        }
        if (tail) {
            hv0[4] = *(const s16x4*)(hr0 + ctail);
            ev0[4] = *(const s16x4*)(er0 + ctail);
        }
#pragma unroll
        for (int rep = 0; rep < 5; rep++) {
            if (rep == 4 && !tail) continue;
            acc[rep].x += fmaxf(0.f, bf2f(hv0[rep].x) + bf2f(ev0[rep].x));
            acc[rep].y += fmaxf(0.f, bf2f(hv0[rep].y) + bf2f(ev0[rep].y));
            acc[rep].z += fmaxf(0.f, bf2f(hv0[rep].z) + bf2f(ev0[rep].z));
            acc[rep].w += fmaxf(0.f, bf2f(hv0[rep].w) + bf2f(ev0[rep].w));
        }
    }

    const short* hn = h_in + (size_t)n * HDIM;
    short* zr = z + (size_t)n * HDIM;
#pragma unroll
    for (int rep = 0; rep < 5; rep++) {
        if (rep == 4 && !tail) continue;
        int c = rep < 4 ? rep * 64 + l16 * 4 : ctail;
        s16x4 hv = *(const s16x4*)(hn + c);
        s16x4 o;
        o.x = f2bf(fmaf(e1, bf2f(hv.x), acc[rep].x));
        o.y = f2bf(fmaf(e1, bf2f(hv.y), acc[rep].y));
        o.z = f2bf(fmaf(e1, bf2f(hv.z), acc[rep].z));
        o.w = f2bf(fmaf(e1, bf2f(hv.w), acc[rep].w));
        *(s16x4*)(zr + c) = o;
    }
}

// ---------------------------------------------------------------------------
// MLP kernel v7 (REVERT, best verified: 312 µs/dispatch, total 2281.6 µs):
// W b-frags direct global->register (zero cross-wave reuse), only Zs/Ys in
// LDS, 12 barriers, full unroll of both k-loops (compiler gets the whole
// body as scheduling window). v8 prefetch-queue: neutral (compiler folds).
// v9 (3blk via intensity cut): -32%. v10 (3blk via Zs removal): HBM-bound.
// v11 (density x2): VGPR spill. Local optimum under {VGPR, LDS, coalescing,
// intensity} constraints. LDS: Zs 40960 + Ys 17408 = 58368 B -> 2 blocks/CU.
// ---------------------------------------------------------------------------
#define ZSTRIDE 320
#define YS_OFF (64 * ZSTRIDE)                  /* 20480 shorts */
#define YST 136
#define LDS_SHORTS (YS_OFF + 64 * YST)         /* 29184 shorts = 58368 B */

__launch_bounds__(256, 2)
__global__ void mlp_kernel(const short* __restrict__ zin,
                           short* __restrict__ hout,
                           const short* __restrict__ Wt1,
                           const short* __restrict__ Wt2,
                           const float* __restrict__ b1l,
                           const float* __restrict__ gammal,
                           const float* __restrict__ betal,
                           const float* __restrict__ meanl,
                           const float* __restrict__ varl,
                           const float* __restrict__ b2l) {
    __shared__ short lds[LDS_SHORTS];
    int tid = threadIdx.x;
    int wng = tid >> 6;          // wave = N-group 0..3
    int lane = tid & 63;
    int quad = lane >> 4;
    int l16 = lane & 15;
    int row0 = blockIdx.x * 64;

    // ---- stage Zs: 64 rows x 320 shorts (incl. spill into next row, killed
    // by W zero-pad for k>=300), XOR-swizzled 16B chunks (v4-verified) ----
    {
        const short* zbase = zin + (size_t)row0 * HDIM;
        for (int i = tid; i < 64 * 40; i += 256) {
            int r = i / 40;
            int cs = i - r * 40;
            const short* srcp = zbase + r * HDIM + cs * 8;
            s16x4 v0 = *(const s16x4*)srcp;
            s16x4 v1 = *(const s16x4*)(srcp + 4);
            int d = r * ZSTRIDE + ((cs ^ (r & 7)) << 3);
            *(s16x4*)&lds[d] = v0;
            *(s16x4*)&lds[d + 4] = v1;
        }
    }

    f32x4v acc2[4][5];
#pragma unroll
    for (int rt = 0; rt < 4; rt++)
#pragma unroll
        for (int ct = 0; ct < 5; ct++) acc2[rt][ct] = (f32x4v){0.f, 0.f, 0.f, 0.f};

    __syncthreads();   // Zs published

    for (int cc = 0; cc < 5; cc++) {
        // ---------- stage 1: C1[64 x 128] = Z @ W1[:, cc*128..+127] ----------
        f32x4v acc1[4][2];
#pragma unroll
        for (int rt = 0; rt < 4; rt++)
#pragma unroll
            for (int ct = 0; ct < 2; ct++) acc1[rt][ct] = (f32x4v){0.f, 0.f, 0.f, 0.f};

#pragma unroll
        for (int kb = 0; kb < 10; kb++) {
            // b-frags first (longest latency: L2 ~200-400 cyc)
            s16x8 b[2];
#pragma unroll
            for (int ct = 0; ct < 2; ct++)
                b[ct] = *(const s16x8*)&Wt1[
                    ((size_t)(((cc * 8 + wng * 2 + ct) * 10 + kb) * 64) + lane) * 8];
            int ks = kb * 32 + quad * 8;
            s16x8 a[4];
#pragma unroll
            for (int rt = 0; rt < 4; rt++)
                a[rt] = *(const s16x8*)&lds[(rt * 16 + l16) * ZSTRIDE
                                            + (ks ^ ((l16 & 7) << 3))];
#pragma unroll
            for (int ct = 0; ct < 2; ct++)
#pragma unroll
                for (int rt = 0; rt < 4; rt++)
                    acc1[rt][ct] = __builtin_amdgcn_mfma_f32_16x16x32_bf16(
                        a[rt], b[ct], acc1[rt][ct], 0, 0, 0);
        }
        __syncthreads();   // stage-2 (cc-1) Ys readers done
        // ---------- epilogue: BN + ReLU -> Ys (verbatim v3) ----------
#pragma unroll
        for (int ct = 0; ct < 2; ct++) {
            int kc = wng * 32 + ct * 16 + l16;
            int col = cc * 128 + kc;
            bool valid = col < H2DIM;
            float s = 0.f, sh = 0.f;
            if (valid) {
                s = gammal[col] * rsqrtf(varl[col] + 1e-5f);
                sh = betal[col] + (b1l[col] - meanl[col]) * s;
            }
#pragma unroll
            for (int rt = 0; rt < 4; rt++)
#pragma unroll
                for (int rr = 0; rr < 4; rr++) {
                    float v = valid ? fmaxf(0.f, fmaf(acc1[rt][ct][rr], s, sh)) : 0.f;
                    lds[YS_OFF + (rt * 16 + quad * 4 + rr) * YST + kc] = f2bf(v);
                }
        }
        __syncthreads();   // Ys published
        // ---------- stage 2: acc2 += Ys @ W2[cc*128.., :] ----------
#pragma unroll
        for (int kbl = 0; kbl < 4; kbl++) {
            // b-frags first
            s16x8 b[5];
#pragma unroll
            for (int ct = 0; ct < 5; ct++)
                b[ct] = *(const s16x8*)&Wt2[
                    ((size_t)(((wng * 5 + ct) * 20 + cc * 4 + kbl) * 64) + lane) * 8];
            int ks = kbl * 32 + quad * 8;
            s16x8 a[4];
#pragma unroll
            for (int rt = 0; rt < 4; rt++)
                a[rt] = *(const s16x8*)&lds[YS_OFF + (rt * 16 + l16) * YST + ks];
#pragma unroll
            for (int ct = 0; ct < 5; ct++)
#pragma unroll
                for (int rt = 0; rt < 4; rt++)
                    acc2[rt][ct] = __builtin_amdgcn_mfma_f32_16x16x32_bf16(
                        a[rt], b[ct], acc2[rt][ct], 0, 0, 0);
        }
    }

    // ---------- final epilogue (verbatim v3): h-tile (stride 300) into Zs
    // region, then coalesced contiguous copy-out. Safe: after cc=4's
    // Ys-publish barrier, lagging waves only read Ys/global, never Zs. ----
#pragma unroll
    for (int ct = 0; ct < 5; ct++) {
        int col = wng * 80 + ct * 16 + l16;
        if (col < HDIM) {
            float bb = b2l[col];
#pragma unroll
            for (int rt = 0; rt < 4; rt++)
#pragma unroll
                for (int rr = 0; rr < 4; rr++) {
                    int rrow = rt * 16 + quad * 4 + rr;
                    lds[rrow * HDIM + col] = f2bf(acc2[rt][ct][rr] + bb);
                }
        }
    }
    __syncthreads();
    for (int i = tid; i < 64 * 75; i += 256) {
        *(s16x4*)&hout[(size_t)row0 * HDIM + i * 4] = *(const s16x4*)&lds[i * 4];
    }
}

// ---------------------------------------------------------------------------
// Mean pool per graph (batch sorted) + classifier (vectorized)
// ---------------------------------------------------------------------------
__device__ int lower_bound_dev(const int* a, int n, int v) {
    int lo = 0, hi = n;
    while (lo < hi) {
        int mid = (lo + hi) >> 1;
        if (a[mid] < v) lo = mid + 1; else hi = mid;
    }
    return lo;
}

__global__ void pool_kernel(const short* __restrict__ h,
                            const int* __restrict__ batch,
                            const float* __restrict__ cls_W,
                            const float* __restrict__ cls_b,
                            float* __restrict__ out) {
    __shared__ int seg[2];
    __shared__ float r0s[256], r1s[256];
    int g = blockIdx.x;
    int t = threadIdx.x;
    if (t == 0) {
        seg[0] = lower_bound_dev(batch, N_NODES, g);
        seg[1] = lower_bound_dev(batch, N_NODES, g + 1);
    }
    __syncthreads();
    int s = seg[0], e = seg[1];
    float inv = 1.f / fmaxf((float)(e - s), 1.f);
    float p0 = 0.f, p1 = 0.f;
    if (t < 75) {
        int c = t * 4;
        float4 sum = {0.f, 0.f, 0.f, 0.f};
        for (int n = s; n < e; n++) {
            s16x4 v = *(const s16x4*)&h[(size_t)n * HDIM + c];
            sum.x += bf2f(v.x);
            sum.y += bf2f(v.y);
            sum.z += bf2f(v.z);
            sum.w += bf2f(v.w);
        }
        float4 gf = {sum.x * inv, sum.y * inv, sum.z * inv, sum.w * inv};
        *(float4*)&out[2 * N_GRAPHS + (size_t)g * HDIM + c] = gf;
        p0 = gf.x * cls_W[c * 2] + gf.y * cls_W[(c + 1) * 2]
           + gf.z * cls_W[(c + 2) * 2] + gf.w * cls_W[(c + 3) * 2];
        p1 = gf.x * cls_W[c * 2 + 1] + gf.y * cls_W[(c + 1) * 2 + 1]
           + gf.z * cls_W[(c + 2) * 2 + 1] + gf.w * cls_W[(c + 3) * 2 + 1];
    }
    r0s[t] = p0;
    r1s[t] = p1;
    __syncthreads();
    for (int st = 128; st > 0; st >>= 1) {
        if (t < st) { r0s[t] += r0s[t + st]; r1s[t] += r1s[t + st]; }
        __syncthreads();
    }
    if (t == 0) {
        out[g * 2 + 0] = r0s[0] + cls_b[0];
        out[g * 2 + 1] = r1s[0] + cls_b[1];
    }
}

// ---------------------------------------------------------------------------
extern "C" void kernel_launch(void* const* d_in, const int* in_sizes, int n_in,
                              void* d_out, int out_size, void* d_ws, size_t ws_size,
                              hipStream_t stream) {
    const int* x          = (const int*)d_in[0];
    const int* edge_index = (const int*)d_in[1];
    const int* edge_attr  = (const int*)d_in[2];
    const int* batch      = (const int*)d_in[3];
    const float* atom_emb = (const float*)d_in[4];
    const float* bond_emb = (const float*)d_in[5];
    const float* eps      = (const float*)d_in[6];
    const float* W1       = (const float*)d_in[7];
    const float* b1       = (const float*)d_in[8];
    const float* bn_gamma = (const float*)d_in[9];
    const float* bn_beta  = (const float*)d_in[10];
    const float* bn_mean  = (const float*)d_in[11];
    const float* bn_var   = (const float*)d_in[12];
    const float* W2       = (const float*)d_in[13];
    const float* b2       = (const float*)d_in[14];
    const float* cls_W    = (const float*)d_in[15];
    const float* cls_b    = (const float*)d_in[16];
    float* out = (float*)d_out;

    char* base = (char*)d_ws;
    const size_t OFF_HA   = 0;                       // 120,000,000
    const size_t OFF_HB   = 120000000;               // 120,000,000 (z / ping-pong)
    const size_t OFF_WT1  = 240000000;               //   2,048,000
    const size_t OFF_WT2  = 242048000;               //   2,048,000
    const size_t OFF_ETAB = 244096000;               //   2,490,368
    const size_t OFF_SIDX = 246586368;               //   1,600,000
    const size_t OFF_OFFS = 248186368;               //     800,016
    const size_t OFF_BSUM = 248986384;               //         784
    const size_t TOTAL    = 248987168;

    if (ws_size < TOTAL) {
        float mb = (float)(ws_size >> 20);
        diag_kernel<<<(out_size + 255) / 256, 256, 0, stream>>>(out, out_size, mb);
        return;
    }

    short* hA   = (short*)(base + OFF_HA);
    short* hB   = (short*)(base + OFF_HB);
    short* Wt1s = (short*)(base + OFF_WT1);
    short* Wt2s = (short*)(base + OFF_WT2);
    short* etab = (short*)(base + OFF_ETAB);
    int*   sidx = (int*)(base + OFF_SIDX);
    int*   offs = (int*)(base + OFF_OFFS);
    int*   bsum = (int*)(base + OFF_BSUM);

    // ---- edge sort by dst ----
    hipMemsetAsync(offs, 0, SCAN_N * sizeof(int), stream);
    hist_kernel<<<(N_EDGES + 255) / 256, 256, 0, stream>>>(edge_index, offs);
    scan1_kernel<<<196, 256, 0, stream>>>(offs, bsum);
    scan2_kernel<<<1, 256, 0, stream>>>(bsum, 196);
    scan3_kernel<<<(SCAN_N + 255) / 256, 256, 0, stream>>>(offs, bsum);
    scatter_kernel<<<(N_EDGES + 255) / 256, 256, 0, stream>>>(edge_index, edge_attr, offs, sidx);

    // ---- weight swizzle + atom encoder ----
    {
        int total = NLAYERS * 40 * 10 * 64 + NLAYERS * 20 * 20 * 64;
        prep_w_swz<<<(total + 255) / 256, 256, 0, stream>>>(W1, W2, Wt1s, Wt2s);
    }
    atom_kernel<<<(N_NODES * 75 + 255) / 256, 256, 0, stream>>>(x, atom_emb, hA);

    // ---- layers: agg hA->hB(z), mlp hB->hA ----
    for (int l = 0; l < NLAYERS; l++) {
        etab_kernel<<<(4096 * 304 + 255) / 256, 256, 0, stream>>>(
            bond_emb + (size_t)l * 3 * 16 * HDIM, etab);
        agg_kernel<<<N_NODES / 16, 256, 0, stream>>>(
            hA, hB, offs, sidx, etab, eps, l);
        mlp_kernel<<<N_NODES / 64, 256, 0, stream>>>(
            hB, hA,
            Wt1s + (size_t)l * 640 * 320, Wt2s + (size_t)l * 320 * 640,
            b1 + l * H2DIM, bn_gamma + l * H2DIM, bn_beta + l * H2DIM,
            bn_mean + l * H2DIM, bn_var + l * H2DIM, b2 + l * HDIM);
    }

    // ---- pool + classifier ----
    pool_kernel<<<N_GRAPHS, 256, 0, stream>>>(hA, batch, cls_W, cls_b, out);
}